// Round 10
// baseline (351.402 us; speedup 1.0000x reference)
//
#include <hip/hip_runtime.h>
#include <math.h>

#define PI_F 3.14159265358979323846f

__device__ __forceinline__ float gelu_f(float x){ return 0.5f*x*(1.0f+erff(x*0.7071067811865475f)); }
__device__ __forceinline__ float sigm_f(float x){ return 1.0f/(1.0f+expf(-x)); }

// native vector type for nontemporal builtins (HIP_vector_type is rejected by the builtin)
typedef float nf4 __attribute__((ext_vector_type(4)));
__device__ __forceinline__ float4 nt_load4(const float4* p){
    nf4 v = __builtin_nontemporal_load((const nf4*)p);
    return make_float4(v.x, v.y, v.z, v.w);
}
__device__ __forceinline__ void nt_store4(float4* p, float4 v){
    nf4 w; w.x=v.x; w.y=v.y; w.z=v.z; w.w=v.w;
    __builtin_nontemporal_store(w, (nf4*)p);
}

// B=8, H=W=64, HW=4096, NP=32768, FC=768, RC=8, P=8, K=9

// ---------------- k_conv1: fp1 1x1 conv 768->8 with IN-BLOCK channel reduction -> t1 ----------------
// grid 512: bln = b*64 + f4chunk; block owns 16 f4 (64 px). 16 groups x 16 threads; group g = ch 48g..48g+47
__global__ void __launch_bounds__(256) k_conv1(const float* __restrict__ fm,
                        const float* __restrict__ w1, const float* __restrict__ b1,
                        const float* __restrict__ pd,
                        float* __restrict__ t1, float* __restrict__ klg){
    __shared__ float wl[768*8];          // 24 KB, wl[c*8+co]
    __shared__ float4 pT[16][8][16];     // 32 KB partials [group][co][f4]
    int bln = blockIdx.x;
    int tid = threadIdx.x;
    int b = bln>>6;
    int q4base = (bln&63)<<4;            // f4 offset within batch plane
    for (int i=tid;i<6144;i+=256){ int c=i>>3, co=i&7; wl[i]=w1[co*768 + c]; }
    __syncthreads();
    int f4i = tid&15, grp = tid>>4;      // grp 0..15
    int q4 = q4base + f4i;
    const float4* fm4 = (const float4*)fm;
    float4 acc[8];
    #pragma unroll
    for(int co=0;co<8;co++) acc[co]=make_float4(0.f,0.f,0.f,0.f);
    int ch0 = grp*48;
    #pragma unroll 4
    for(int c=0;c<48;c++){
        int ch = ch0 + c;
        float4 x = nt_load4(&fm4[(size_t)(b*768 + ch)*1024 + q4]);
        #pragma unroll
        for(int co=0;co<8;co++){
            float wv = wl[(ch<<3)+co];
            acc[co].x += wv*x.x; acc[co].y += wv*x.y; acc[co].z += wv*x.z; acc[co].w += wv*x.w;
        }
    }
    #pragma unroll
    for(int co=0;co<8;co++) pT[grp][co][f4i]=acc[co];
    __syncthreads();
    if(tid<128){
        int co=tid>>4, fi=tid&15;
        float4 s=make_float4(0.f,0.f,0.f,0.f);
        #pragma unroll
        for(int g=0;g<16;g++){
            float4 v=pT[g][co][fi];
            s.x+=v.x; s.y+=v.y; s.z+=v.z; s.w+=v.w;
        }
        float bb=b1[co];
        float4 o;
        o.x=gelu_f(s.x+bb); o.y=gelu_f(s.y+bb); o.z=gelu_f(s.z+bb); o.w=gelu_f(s.w+bb);
        ((float4*)t1)[(size_t)co*8192 + (b<<10) + q4base + fi] = o;
    }

    // ---- bank build (one block only) ----
    if(bln==0){
        __shared__ float ridge[648];
        __shared__ float pmS[8], pdenS[8];
        for(int t=tid;t<648;t+=256){
            int p=t/81, idx=t-p*81;
            int i=idx/9, j=idx-i*9;
            float ay=-1.f+0.25f*(float)i;
            float ax=-1.f+0.25f*(float)j;
            float ang=2.f*PI_F*(float)p*0.125f;
            const float Ls[3]={0.45f,0.75f,1.05f};
            const float Ws[3]={0.14f,0.20f,0.28f};
            float L=Ls[p%3], Wd=Ws[(p/3)%3];
            float cs=cosf(ang), sn=sinf(ang);
            float xr=ax*cs+ay*sn;
            float yr=-ax*sn+ay*cs;
            float tp=1.f-fminf(fabsf(xr)/L,1.f);
            float taper=powf(tp,1.5f);
            float core=expf(-0.5f*((xr/L)*(xr/L)+(yr/Wd)*(yr/Wd)));
            ridge[t]=taper*core*fmaxf(1.f-(yr/Wd)*(yr/Wd),0.f);
        }
        __syncthreads();
        {
            int p=tid>>5, k=tid&31;
            float s=0.f;
            for(int e=k;e<81;e+=32) s+=ridge[p*81+e];
            for(int off=16;off>0;off>>=1) s+=__shfl_down(s,off,32);
            if(k==0) pmS[p]=s*(1.f/81.f);
        }
        __syncthreads();
        {
            int p=tid>>5, k=tid&31;
            float m=pmS[p];
            float s=0.f;
            for(int e=k;e<81;e+=32) s+=fabsf(ridge[p*81+e]-m);
            for(int off=16;off>0;off>>=1) s+=__shfl_down(s,off,32);
            if(k==0) pdenS[p]=fmaxf(s,1e-6f);
        }
        __syncthreads();
        for(int t=tid;t<648;t+=256){
            int p=t/81;
            klg[t]=(ridge[t]-pmS[p])/pdenS[p]+0.05f*pd[t];
        }
    }
}

// ---------------- k_mid: conv2 (recomputed in-tile) + chp + 9x9 resp + top2, fused ----------------
// grid 512: bl = b*64+y, ONE output row per block. cm computed for 11 halo rows from 13 t1 rows.
__global__ void __launch_bounds__(256) k_mid(const float* __restrict__ t1,
    const float* __restrict__ w2, const float* __restrict__ b2,
    const float* __restrict__ klg, const float* __restrict__ theta,
    const float* __restrict__ length, const float* __restrict__ width,
    const float* __restrict__ plog,
    float* __restrict__ carrier, float* __restrict__ absc,
    float* __restrict__ csraw, float* __restrict__ ss0, float* __restrict__ bpart){
    __shared__ float t1T[13][8][64];   // t1 rows y-6..y+6, 26 KB
    __shared__ float w2s[576];
    __shared__ float cmT[11][64];      // cm rows y-5..y+5
    __shared__ float absS[64];         // absc row y
    __shared__ float chpT[9][64];      // chp rows y-4..y+4
    __shared__ float klS[648];
    __shared__ float mg[64][16];
    int tid=threadIdx.x, bl=blockIdx.x;
    int b=bl>>6, y=bl&63;
    for(int i=tid;i<576;i+=256) w2s[i]=w2[i];
    for(int i=tid;i<648;i+=256) klS[i]=klg[i];
    // stage t1 rows y-6..y+6 (13 x 8 x 64)
    for(int j=tid;j<6656;j+=256){
        int rr=j>>9, rem=j&511, ci=rem>>6, x=rem&63;
        int gy=y-6+rr;
        float v=0.f;
        if(gy>=0&&gy<64) v=t1[(size_t)ci*32768+(b<<12)+(gy<<6)+x];
        t1T[rr][ci][x]=v;
    }
    __syncthreads();
    // cm rows y-5..y+5; carrier/absc at central row (r==5)
    for(int j=tid;j<704;j+=256){
        int r=j>>6, x=j&63;
        int gy=y-5+r;
        float cmv=0.f;
        if(gy>=0&&gy<64){
            float acc[8];
            #pragma unroll
            for(int co=0;co<8;co++) acc[co]=b2[co];
            for(int ci=0;ci<8;ci++){
                #pragma unroll
                for(int dr=0;dr<3;dr++){
                    #pragma unroll
                    for(int dx=-1;dx<=1;dx++){
                        int xx=x+dx;
                        float v=(xx>=0&&xx<64)?t1T[r+dr][ci][xx]:0.f;
                        int ti=dr*3+(dx+1);
                        #pragma unroll
                        for(int co=0;co<8;co++) acc[co]+=v*w2s[(co*8+ci)*9+ti];
                    }
                }
            }
            float s=0.f, sa=0.f;
            #pragma unroll
            for(int co=0;co<8;co++){
                float cv=gelu_f(acc[co]);
                s+=cv; sa+=fabsf(cv);
                if(r==5) carrier[((size_t)((b<<3)+co)<<12)+(y<<6)+x]=cv;
            }
            cmv=s*0.125f;
            if(r==5){
                float av=sa*0.125f;
                absc[(b<<12)+(y<<6)+x]=av;
                absS[x]=av;
            }
        }
        cmT[r][x]=cmv;
    }
    __syncthreads();
    // chp rows y-4..y+4
    for(int j=tid;j<576;j+=256){
        int rh=j>>6, x=j&63;
        int gy=y-4+rh;
        float v=0.f;
        if(gy>=0&&gy<64){
            float s=0.f;
            #pragma unroll
            for(int dy=0;dy<3;dy++){
                #pragma unroll
                for(int dx=-1;dx<=1;dx++){
                    int xx=x+dx;
                    if(xx>=0&&xx<64) s+=cmT[rh+dy][xx];
                }
            }
            v=cmT[rh+1][x]-s*(1.f/9.f);
        }
        chpT[rh][x]=v;
    }
    __syncthreads();
    // resp: 9x9 bank conv, 4 groups x 2 protos
    int x=tid&63, qg=tid>>6;
    int gp=(b<<12)+(y<<6)+x;
    float acc2[2]={0.f,0.f};
    float cs=0.f;
    for(int dy=-4;dy<=4;dy++){
        int lr=dy+4;
        for(int dx=-4;dx<=4;dx++){
            int xx=x+dx;
            float v=(xx>=0&&xx<64)?chpT[lr][xx]:0.f;
            int ti=lr*9+(dx+4);
            acc2[0]+=v*klS[(qg*2)*81+ti];
            acc2[1]+=v*klS[(qg*2+1)*81+ti];
            if(qg==0 && dy>=-1&&dy<=1&&dx>=-1&&dx<=1) cs+=fabsf(v);
        }
    }
    float ta=tanhf(theta[gp])*PI_F;
    float lv=sigm_f(length[gp])*0.85f+0.25f;
    float wv=sigm_f(width[gp])*0.22f+0.08f;
    const float Ls[3]={0.45f,0.75f,1.05f};
    const float Ws[3]={0.14f,0.20f,0.28f};
    int pp=(y<<6)+x;
    float bias[2];
    #pragma unroll
    for(int qq=0;qq<2;qq++){
        int q=qg*2+qq;
        float ang=2.f*PI_F*(float)q*0.125f;
        float la=Ls[q%3], wa=Ws[(q/3)%3];
        bias[qq]=plog[((size_t)((b<<3)+q)<<12)+pp]
               +1.25f*cosf(ta-ang)
               -(lv-la)*(lv-la)*(1.f/0.08f)
               -(wv-wa)*(wv-wa)*(1.f/0.01f);
    }
    float m1,r1,m2,r2;
    if(bias[1]>bias[0]){ m1=bias[1];r1=acc2[1]; m2=bias[0];r2=acc2[0]; }
    else               { m1=bias[0];r1=acc2[0]; m2=bias[1];r2=acc2[1]; }
    mg[x][qg*4+0]=m1; mg[x][qg*4+1]=r1; mg[x][qg*4+2]=m2; mg[x][qg*4+3]=r2;
    __syncthreads();
    if(qg==0){   // wave 0
        float M1=mg[x][0],R1=mg[x][1],M2=mg[x][2],R2=mg[x][3];
        #pragma unroll
        for(int g=1;g<4;g++){
            float m1b=mg[x][g*4],r1b=mg[x][g*4+1],m2b=mg[x][g*4+2],r2b=mg[x][g*4+3];
            if(m1b>M1){
                float nM2,nR2;
                if(m2b>M1){nM2=m2b;nR2=r2b;} else {nM2=M1;nR2=R1;}
                M1=m1b;R1=r1b;M2=nM2;R2=nR2;
            } else if(m1b>M2){
                M2=m1b;R2=r1b;
            }
        }
        float e2=expf(M2-M1);
        float inv=1.0f/(1.0f+e2);
        ss0[gp]=R1*inv + R2*e2*inv;
        float csv=cs*(1.f/9.f);
        csraw[gp]=csv;
        // single-wave reductions: csraw min/max + absc sum/min/max
        float av=absS[x];
        float sm=av, amn=av, amx=av, cmn=csv, cmx=csv;
        #pragma unroll
        for(int off=32;off>0;off>>=1){
            sm  += __shfl_down(sm,off);
            amn  = fminf(amn,__shfl_down(amn,off));
            amx  = fmaxf(amx,__shfl_down(amx,off));
            cmn  = fminf(cmn,__shfl_down(cmn,off));
            cmx  = fmaxf(cmx,__shfl_down(cmx,off));
        }
        if(x==0){
            bpart[bl*8+0]=sm;
            bpart[bl*8+1]=cmn;
            bpart[bl*8+2]=cmx;
            bpart[bl*8+3]=amn;
            bpart[bl*8+4]=amx;
        }
    }
}

// ---------------- k_out: gate + h + pm2 fused; grid 512 (1 row / block) ----------------
__global__ void __launch_bounds__(256) k_out(const float* __restrict__ ss0,
    const float* __restrict__ csraw, const float* __restrict__ absc,
    const float* __restrict__ objn, const float* __restrict__ alpha,
    const float* __restrict__ theta, const float* __restrict__ curv,
    const float* __restrict__ carrier, const float* __restrict__ bpart,
    const float* __restrict__ w3, const float* __restrict__ b3,
    const float* __restrict__ w4, const float* __restrict__ b4,
    float* __restrict__ out){
    __shared__ float hS[8][64];      // 2 KB
    __shared__ float w4s[768*8];     // 24 KB
    __shared__ float b4s[768];
    __shared__ float wl3[96];
    __shared__ float bl3[8];
    __shared__ float evT[13*64];     // ev rows y-6..y+6
    __shared__ float gmT[13*64];     // sigm gate, same rows
    __shared__ float eT[9*64];       // erode rows y-4..y+4
    __shared__ float m1T[5*64];      // dilate rows y-2..y+2
    __shared__ float obT[3*64];      // sigm(objn) rows y-1..y+1
    __shared__ float red5[5];
    int tid=threadIdx.x;
    int bln=blockIdx.x;              // 0..511
    int b=bln>>6, y=bln&63;
    for(int i=tid;i<6144;i+=256) w4s[i]=w4[i];
    for(int i=tid;i<768;i+=256) b4s[i]=b4[i];
    if(tid<96) wl3[tid]=w3[tid];
    if(tid<8) bl3[tid]=b3[tid];
    // ---- batch stats reduction (wave 0) ----
    if(tid<64){
        const float* bp=&bpart[((size_t)b*64+tid)*8];
        float sm=bp[0], cmn=bp[1], cmx=bp[2], amn=bp[3], amx=bp[4];
        #pragma unroll
        for(int off=32;off>0;off>>=1){
            sm  += __shfl_down(sm,off);
            cmn  = fminf(cmn,__shfl_down(cmn,off));
            cmx  = fmaxf(cmx,__shfl_down(cmx,off));
            amn  = fminf(amn,__shfl_down(amn,off));
            amx  = fmaxf(amx,__shfl_down(amx,off));
        }
        if(tid==0){
            float den=fmaxf(sm*(1.0f/4096.0f),1e-6f);
            red5[0]=den; red5[1]=cmn; red5[2]=cmx; red5[3]=amn/den; red5[4]=amx/den;
        }
    }
    __syncthreads();
    float den=red5[0], cmn=red5[1], dmn=red5[3];
    float cinv = 1.0f/fmaxf(red5[2]-cmn,1e-6f);
    float dinv = 1.0f/fmaxf(red5[4]-dmn,1e-6f);
    // ---- ev / gm tiles (13 rows), objn tile (3 rows) ----
    for(int j=tid;j<832;j+=256){
        int r=j>>6, x=j&63; int gy=y-6+r;
        float ev=0.f;
        if(gy>=0&&gy<64){
            int gp=(b<<12)+(gy<<6)+x;
            float cs=(csraw[gp]-cmn)*cinv;
            float d=absc[gp]/den;
            ev=0.65f*cs+0.35f*((d-dmn)*dinv);
        }
        evT[j]=ev;
        gmT[j]=sigm_f((ev-0.2f)*(1.0f/0.08f));
    }
    for(int j=tid;j<192;j+=256){
        int r=j>>6,x=j&63; int gy=y-1+r;
        obT[j]=(gy>=0&&gy<64)?sigm_f(objn[(b<<12)+(gy<<6)+x]):0.f;
    }
    __syncthreads();
    // ---- erode rows y-4..y+4 ----
    for(int j=tid;j<576;j+=256){
        int r=j>>6,x=j&63; int gy=y-4+r;
        float m=0.f;
        if(gy>=0&&gy<64){
            m=1.f;
            for(int dy=-2;dy<=2;dy++){int yy=gy+dy; if(yy<0||yy>=64)continue;
                int lr=yy-(y-6);
                for(int dx=-2;dx<=2;dx++){int xx=x+dx; if(xx<0||xx>=64)continue;
                    if(evT[(lr<<6)+xx]<0.2f) m=0.f;}}
        }
        eT[j]=m;
    }
    __syncthreads();
    // ---- dilate e -> m1, rows y-2..y+2 ----
    for(int j=tid;j<320;j+=256){
        int r=j>>6,x=j&63; int gy=y-2+r;
        float m=0.f;
        if(gy>=0&&gy<64){
            m=-1e30f;
            for(int dy=-2;dy<=2;dy++){int yy=gy+dy; if(yy<0||yy>=64)continue;
                int lr=yy-(y-4);
                for(int dx=-2;dx<=2;dx++){int xx=x+dx; if(xx<0||xx>=64)continue;
                    m=fmaxf(m,eT[(lr<<6)+xx]);}}
        }
        m1T[j]=m;
    }
    __syncthreads();
    // ---- phase H: gate finish + h (wave 0, one thread per pixel of row y) ----
    if(tid<64){
        int x=tid;
        int gp=(b<<12)+(y<<6)+x;
        float m2=-1e30f, gx=-1e30f;
        for(int dy=-2;dy<=2;dy++){int yy=y+dy; if(yy<0||yy>=64)continue;
            int lr1=yy-(y-2), lr2=yy-(y-6);
            for(int dx=-2;dx<=2;dx++){int xx=x+dx; if(xx<0||xx>=64)continue;
                m2=fmaxf(m2,m1T[(lr1<<6)+xx]);
                gx=fmaxf(gx,gmT[(lr2<<6)+xx]);}}
        float s=0.f;
        for(int dy=-1;dy<=1;dy++){int yy=y+dy; if(yy<0||yy>=64)continue;
            int lr=yy-(y-1);
            for(int dx=-1;dx<=1;dx++){int xx=x+dx; if(xx<0||xx>=64)continue;
                s+=obT[(lr<<6)+xx];}}
        float blob=s*(1.0f/9.0f);
        float gate=gx*m2;
        float d=absc[gp]/den;
        float sgv=sigm_f(alpha[gp])*blob*gate*(0.7f+0.3f*fminf(fmaxf(d,0.f),2.f));
        // h
        const float* base = ss0 + (b<<12);
        float ssum=0.f;
        for(int dy=-1;dy<=1;dy++){int yy=y+dy; if(yy<0||yy>=64)continue;
            for(int dx=-1;dx<=1;dx++){int xx=x+dx;if(xx<0||xx>=64)continue;
                ssum+=base[(yy<<6)+xx];}}
        float ss1 = base[(y<<6)+x]-ssum*(1.0f/9.0f);
        float cu = tanhf(curv[gp]);
        float ssv = sgv*ss1*(1.0f+0.15f*cu);
        float ta = tanhf(theta[gp])*PI_F;
        float dxv=cosf(ta), dyv=sinf(ta);
        float car[8];
        #pragma unroll
        for(int ci=0;ci<8;ci++) car[ci]=carrier[((size_t)((b<<3)+ci)<<12)+(y<<6)+x];
        #pragma unroll
        for(int co=0;co<8;co++){
            const float* w=&wl3[co*12];
            float t = w[8] + w[9]*dxv + w[10]*dyv + w[11]*cu;
            #pragma unroll
            for(int ci=0;ci<8;ci++) t += w[ci]*car[ci];
            hS[co][tid] = gelu_f(bl3[co] + ssv*t);
        }
    }
    __syncthreads();
    // ---- phase 2: 8->768 expansion, NT stores ----
    int px4 = tid&15;          // f4 px within block
    int cg = tid>>4;           // 0..15, 48 co each
    int q0 = bln*16 + px4;     // GLOBAL f4 index (0..8191)
    int bb_ = q0>>10;
    int ql = q0 & 1023;        // within-batch f4 index
    float4 hv[8];
    #pragma unroll
    for(int ci=0;ci<8;ci++) hv[ci]=*(const float4*)&hS[ci][px4<<2];
    float4* o4=(float4*)out;
    for(int k=0;k<48;k++){
        int co=cg*48+k;
        float bv=b4s[co];
        float4 o=make_float4(bv,bv,bv,bv);
        const float* w=&w4s[co<<3];
        #pragma unroll
        for(int ci=0;ci<8;ci++){
            float wv=w[ci];
            o.x+=wv*hv[ci].x; o.y+=wv*hv[ci].y; o.z+=wv*hv[ci].z; o.w+=wv*hv[ci].w;
        }
        nt_store4(&o4[(size_t)(bb_*768+co)*1024 + ql], o);
    }
}

extern "C" void kernel_launch(void* const* d_in, const int* in_sizes, int n_in,
                              void* d_out, int out_size, void* d_ws, size_t ws_size,
                              hipStream_t stream) {
    const float* fm     =(const float*)d_in[0];
    const float* theta  =(const float*)d_in[1];
    const float* length =(const float*)d_in[2];
    const float* width  =(const float*)d_in[3];
    const float* curv   =(const float*)d_in[4];
    const float* alpha  =(const float*)d_in[5];
    const float* objn   =(const float*)d_in[6];
    const float* plog   =(const float*)d_in[7];
    const float* fp1w   =(const float*)d_in[8];
    const float* fp1b   =(const float*)d_in[9];
    const float* fp2w   =(const float*)d_in[10];
    const float* fp2b   =(const float*)d_in[11];
    const float* pm1w   =(const float*)d_in[12];
    const float* pm1b   =(const float*)d_in[13];
    const float* pm2w   =(const float*)d_in[14];
    const float* pm2b   =(const float*)d_in[15];
    const float* pdelta =(const float*)d_in[16];

    float* ws=(float*)d_ws;
    float* t1      = ws;                  // 262144
    float* carrier = t1 + 262144;         // 262144
    float* absc    = carrier + 262144;    // 32768
    float* csraw   = absc + 32768;        // 32768
    float* ss0     = csraw + 32768;       // 32768
    float* bpart   = ss0 + 32768;         // 4096 (512 records x 8)
    float* klg     = bpart + 4096;        // 648
    float* out     = (float*)d_out;

    k_conv1<<<512, 256, 0, stream>>>(fm, fp1w, fp1b, pdelta, t1, klg);
    k_mid  <<<512, 256, 0, stream>>>(t1, fp2w, fp2b, klg, theta, length, width, plog,
                                     carrier, absc, csraw, ss0, bpart);
    k_out  <<<512, 256, 0, stream>>>(ss0, csraw, absc, objn, alpha, theta, curv,
                                     carrier, bpart, pm1w, pm1b, pm2w, pm2b, out);
}

// Round 11
// 284.079 us; speedup vs baseline: 1.2370x; 1.2370x over previous
//
#include <hip/hip_runtime.h>
#include <math.h>

#define PI_F 3.14159265358979323846f

__device__ __forceinline__ float gelu_f(float x){ return 0.5f*x*(1.0f+erff(x*0.7071067811865475f)); }
__device__ __forceinline__ float sigm_f(float x){ return 1.0f/(1.0f+expf(-x)); }

// native vector type for nontemporal builtins (HIP_vector_type is rejected by the builtin)
typedef float nf4 __attribute__((ext_vector_type(4)));
__device__ __forceinline__ float4 nt_load4(const float4* p){
    nf4 v = __builtin_nontemporal_load((const nf4*)p);
    return make_float4(v.x, v.y, v.z, v.w);
}
__device__ __forceinline__ void nt_store4(float4* p, float4 v){
    nf4 w; w.x=v.x; w.y=v.y; w.z=v.z; w.w=v.w;
    __builtin_nontemporal_store(w, (nf4*)p);
}

// B=8, H=W=64, HW=4096, NP=32768, FC=768, RC=8, P=8, K=9

// ---------------- k_conv1: fp1 1x1 conv 768->8 with IN-BLOCK channel reduction -> t1 ----------------
// grid 512: bln = b*64 + f4chunk; block owns 16 f4 (64 px). 16 groups x 16 threads; group g = ch 48g..48g+47
__global__ void __launch_bounds__(256) k_conv1(const float* __restrict__ fm,
                        const float* __restrict__ w1, const float* __restrict__ b1,
                        const float* __restrict__ pd,
                        float* __restrict__ t1, float* __restrict__ klg){
    __shared__ float wl[768*8];          // 24 KB, wl[c*8+co]
    __shared__ float4 pT[16][8][16];     // 32 KB partials [group][co][f4]
    int bln = blockIdx.x;
    int tid = threadIdx.x;
    int b = bln>>6;
    int q4base = (bln&63)<<4;            // f4 offset within batch plane
    for (int i=tid;i<6144;i+=256){ int c=i>>3, co=i&7; wl[i]=w1[co*768 + c]; }
    __syncthreads();
    int f4i = tid&15, grp = tid>>4;      // grp 0..15
    int q4 = q4base + f4i;
    const float4* fm4 = (const float4*)fm;
    float4 acc[8];
    #pragma unroll
    for(int co=0;co<8;co++) acc[co]=make_float4(0.f,0.f,0.f,0.f);
    int ch0 = grp*48;
    #pragma unroll 4
    for(int c=0;c<48;c++){
        int ch = ch0 + c;
        float4 x = nt_load4(&fm4[(size_t)(b*768 + ch)*1024 + q4]);
        #pragma unroll
        for(int co=0;co<8;co++){
            float wv = wl[(ch<<3)+co];
            acc[co].x += wv*x.x; acc[co].y += wv*x.y; acc[co].z += wv*x.z; acc[co].w += wv*x.w;
        }
    }
    #pragma unroll
    for(int co=0;co<8;co++) pT[grp][co][f4i]=acc[co];
    __syncthreads();
    if(tid<128){
        int co=tid>>4, fi=tid&15;
        float4 s=make_float4(0.f,0.f,0.f,0.f);
        #pragma unroll
        for(int g=0;g<16;g++){
            float4 v=pT[g][co][fi];
            s.x+=v.x; s.y+=v.y; s.z+=v.z; s.w+=v.w;
        }
        float bb=b1[co];
        float4 o;
        o.x=gelu_f(s.x+bb); o.y=gelu_f(s.y+bb); o.z=gelu_f(s.z+bb); o.w=gelu_f(s.w+bb);
        ((float4*)t1)[(size_t)co*8192 + (b<<10) + q4base + fi] = o;
    }

    // ---- bank build (one block only) ----
    if(bln==0){
        __shared__ float ridge[648];
        __shared__ float pmS[8], pdenS[8];
        for(int t=tid;t<648;t+=256){
            int p=t/81, idx=t-p*81;
            int i=idx/9, j=idx-i*9;
            float ay=-1.f+0.25f*(float)i;
            float ax=-1.f+0.25f*(float)j;
            float ang=2.f*PI_F*(float)p*0.125f;
            const float Ls[3]={0.45f,0.75f,1.05f};
            const float Ws[3]={0.14f,0.20f,0.28f};
            float L=Ls[p%3], Wd=Ws[(p/3)%3];
            float cs=cosf(ang), sn=sinf(ang);
            float xr=ax*cs+ay*sn;
            float yr=-ax*sn+ay*cs;
            float tp=1.f-fminf(fabsf(xr)/L,1.f);
            float taper=powf(tp,1.5f);
            float core=expf(-0.5f*((xr/L)*(xr/L)+(yr/Wd)*(yr/Wd)));
            ridge[t]=taper*core*fmaxf(1.f-(yr/Wd)*(yr/Wd),0.f);
        }
        __syncthreads();
        {
            int p=tid>>5, k=tid&31;
            float s=0.f;
            for(int e=k;e<81;e+=32) s+=ridge[p*81+e];
            for(int off=16;off>0;off>>=1) s+=__shfl_down(s,off,32);
            if(k==0) pmS[p]=s*(1.f/81.f);
        }
        __syncthreads();
        {
            int p=tid>>5, k=tid&31;
            float m=pmS[p];
            float s=0.f;
            for(int e=k;e<81;e+=32) s+=fabsf(ridge[p*81+e]-m);
            for(int off=16;off>0;off>>=1) s+=__shfl_down(s,off,32);
            if(k==0) pdenS[p]=fmaxf(s,1e-6f);
        }
        __syncthreads();
        for(int t=tid;t<648;t+=256){
            int p=t/81;
            klg[t]=(ridge[t]-pmS[p])/pdenS[p]+0.05f*pd[t];
        }
    }
}

// ---------------- k_mid: conv2 (row-sequential, low-VGPR) + chp + 9x9 resp + top2, fused ----------------
// grid 512: bl = b*64+y, ONE output row per block. cm computed for 11 halo rows from 13 t1 rows.
__global__ void __launch_bounds__(256) k_mid(const float* __restrict__ t1,
    const float* __restrict__ w2, const float* __restrict__ b2,
    const float* __restrict__ klg, const float* __restrict__ theta,
    const float* __restrict__ length, const float* __restrict__ width,
    const float* __restrict__ plog,
    float* __restrict__ carrier, float* __restrict__ absc,
    float* __restrict__ csraw, float* __restrict__ ss0, float* __restrict__ bpart){
    __shared__ float t1T[13][8][64];   // t1 rows y-6..y+6, 26 KB
    __shared__ float w2s[576];
    __shared__ float cmT[11][64];      // cm rows y-5..y+5
    __shared__ float sumS[4][64];
    __shared__ float saS[4][64];
    __shared__ float absS[64];         // absc row y
    __shared__ float chpT[9][64];      // chp rows y-4..y+4
    __shared__ float klS[648];
    __shared__ float mg[64][16];
    int tid=threadIdx.x, bl=blockIdx.x;
    int b=bl>>6, y=bl&63;
    for(int i=tid;i<576;i+=256) w2s[i]=w2[i];
    for(int i=tid;i<648;i+=256) klS[i]=klg[i];
    // stage t1 rows y-6..y+6 (13 x 8 x 64)
    for(int j=tid;j<6656;j+=256){
        int rr=j>>9, rem=j&511, ci=rem>>6, x=rem&63;
        int gy=y-6+rr;
        float v=0.f;
        if(gy>=0&&gy<64) v=t1[(size_t)ci*32768+(b<<12)+(gy<<6)+x];
        t1T[rr][ci][x]=v;
    }
    __syncthreads();
    // cm rows y-5..y+5, ONE ROW AT A TIME with conv2-style mapping (acc[2]/thread, no spill)
    int x=tid&63, cg=tid>>6;           // cg 0..3, channels cg*2, cg*2+1
    float bias0=b2[cg*2], bias1=b2[cg*2+1];
    for(int r=0;r<11;r++){
        int gy=y-5+r;
        float acc0=bias0, acc1=bias1;
        if(gy>=0&&gy<64){
            for(int ci=0;ci<8;ci++){
                #pragma unroll
                for(int dr=0;dr<3;dr++){
                    #pragma unroll
                    for(int dx=-1;dx<=1;dx++){
                        int xx=x+dx;
                        float v=(xx>=0&&xx<64)?t1T[r+dr][ci][xx]:0.f;
                        int ti=dr*3+(dx+1);
                        acc0+=v*w2s[((cg*2  )*8+ci)*9+ti];
                        acc1+=v*w2s[((cg*2+1)*8+ci)*9+ti];
                    }
                }
            }
        }
        float cv0=gelu_f(acc0), cv1=gelu_f(acc1);
        if(gy>=0&&gy<64 && r==5){
            carrier[((size_t)((b<<3)+cg*2  )<<12)+(y<<6)+x]=cv0;
            carrier[((size_t)((b<<3)+cg*2+1)<<12)+(y<<6)+x]=cv1;
        }
        sumS[cg][x]=cv0+cv1;
        saS[cg][x]=fabsf(cv0)+fabsf(cv1);
        __syncthreads();
        if(cg==0){
            float cmv=0.f;
            if(gy>=0&&gy<64){
                cmv=(sumS[0][x]+sumS[1][x]+sumS[2][x]+sumS[3][x])*0.125f;
                if(r==5){
                    float av=(saS[0][x]+saS[1][x]+saS[2][x]+saS[3][x])*0.125f;
                    absc[(b<<12)+(y<<6)+x]=av;
                    absS[x]=av;
                }
            }
            cmT[r][x]=cmv;
        }
        __syncthreads();
    }
    // chp rows y-4..y+4
    for(int j=tid;j<576;j+=256){
        int rh=j>>6, xx0=j&63;
        int gy=y-4+rh;
        float v=0.f;
        if(gy>=0&&gy<64){
            float s=0.f;
            #pragma unroll
            for(int dy=0;dy<3;dy++){
                #pragma unroll
                for(int dx=-1;dx<=1;dx++){
                    int xx=xx0+dx;
                    if(xx>=0&&xx<64) s+=cmT[rh+dy][xx];
                }
            }
            v=cmT[rh+1][xx0]-s*(1.f/9.f);
        }
        chpT[rh][xx0]=v;
    }
    __syncthreads();
    // resp: 9x9 bank conv, 4 groups x 2 protos
    int qg=cg;
    int gp=(b<<12)+(y<<6)+x;
    float acc2[2]={0.f,0.f};
    float cs=0.f;
    for(int dy=-4;dy<=4;dy++){
        int lr=dy+4;
        for(int dx=-4;dx<=4;dx++){
            int xx=x+dx;
            float v=(xx>=0&&xx<64)?chpT[lr][xx]:0.f;
            int ti=lr*9+(dx+4);
            acc2[0]+=v*klS[(qg*2)*81+ti];
            acc2[1]+=v*klS[(qg*2+1)*81+ti];
            if(qg==0 && dy>=-1&&dy<=1&&dx>=-1&&dx<=1) cs+=fabsf(v);
        }
    }
    float ta=tanhf(theta[gp])*PI_F;
    float lv=sigm_f(length[gp])*0.85f+0.25f;
    float wv=sigm_f(width[gp])*0.22f+0.08f;
    const float Ls[3]={0.45f,0.75f,1.05f};
    const float Ws[3]={0.14f,0.20f,0.28f};
    int pp=(y<<6)+x;
    float bias[2];
    #pragma unroll
    for(int qq=0;qq<2;qq++){
        int q=qg*2+qq;
        float ang=2.f*PI_F*(float)q*0.125f;
        float la=Ls[q%3], wa=Ws[(q/3)%3];
        bias[qq]=plog[((size_t)((b<<3)+q)<<12)+pp]
               +1.25f*cosf(ta-ang)
               -(lv-la)*(lv-la)*(1.f/0.08f)
               -(wv-wa)*(wv-wa)*(1.f/0.01f);
    }
    float m1,r1,m2,r2;
    if(bias[1]>bias[0]){ m1=bias[1];r1=acc2[1]; m2=bias[0];r2=acc2[0]; }
    else               { m1=bias[0];r1=acc2[0]; m2=bias[1];r2=acc2[1]; }
    mg[x][qg*4+0]=m1; mg[x][qg*4+1]=r1; mg[x][qg*4+2]=m2; mg[x][qg*4+3]=r2;
    __syncthreads();
    if(qg==0){   // wave 0
        float M1=mg[x][0],R1=mg[x][1],M2=mg[x][2],R2=mg[x][3];
        #pragma unroll
        for(int g=1;g<4;g++){
            float m1b=mg[x][g*4],r1b=mg[x][g*4+1],m2b=mg[x][g*4+2],r2b=mg[x][g*4+3];
            if(m1b>M1){
                float nM2,nR2;
                if(m2b>M1){nM2=m2b;nR2=r2b;} else {nM2=M1;nR2=R1;}
                M1=m1b;R1=r1b;M2=nM2;R2=nR2;
            } else if(m1b>M2){
                M2=m1b;R2=r1b;
            }
        }
        float e2=expf(M2-M1);
        float inv=1.0f/(1.0f+e2);
        ss0[gp]=R1*inv + R2*e2*inv;
        float csv=cs*(1.f/9.f);
        csraw[gp]=csv;
        // single-wave reductions: csraw min/max + absc sum/min/max
        float av=absS[x];
        float sm=av, amn=av, amx=av, cmn=csv, cmx=csv;
        #pragma unroll
        for(int off=32;off>0;off>>=1){
            sm  += __shfl_down(sm,off);
            amn  = fminf(amn,__shfl_down(amn,off));
            amx  = fmaxf(amx,__shfl_down(amx,off));
            cmn  = fminf(cmn,__shfl_down(cmn,off));
            cmx  = fmaxf(cmx,__shfl_down(cmx,off));
        }
        if(x==0){
            bpart[bl*8+0]=sm;
            bpart[bl*8+1]=cmn;
            bpart[bl*8+2]=cmx;
            bpart[bl*8+3]=amn;
            bpart[bl*8+4]=amx;
        }
    }
}

// ---------------- k_out: gate + h + pm2 fused; grid 512 (1 row / block) ----------------
__global__ void __launch_bounds__(256) k_out(const float* __restrict__ ss0,
    const float* __restrict__ csraw, const float* __restrict__ absc,
    const float* __restrict__ objn, const float* __restrict__ alpha,
    const float* __restrict__ theta, const float* __restrict__ curv,
    const float* __restrict__ carrier, const float* __restrict__ bpart,
    const float* __restrict__ w3, const float* __restrict__ b3,
    const float* __restrict__ w4, const float* __restrict__ b4,
    float* __restrict__ out){
    __shared__ float hS[8][64];      // 2 KB
    __shared__ float w4s[768*8];     // 24 KB
    __shared__ float b4s[768];
    __shared__ float wl3[96];
    __shared__ float bl3[8];
    __shared__ float evT[13*64];     // ev rows y-6..y+6
    __shared__ float gmT[13*64];     // sigm gate, same rows
    __shared__ float eT[9*64];       // erode rows y-4..y+4
    __shared__ float m1T[5*64];      // dilate rows y-2..y+2
    __shared__ float obT[3*64];      // sigm(objn) rows y-1..y+1
    __shared__ float red5[5];
    int tid=threadIdx.x;
    int bln=blockIdx.x;              // 0..511
    int b=bln>>6, y=bln&63;
    for(int i=tid;i<6144;i+=256) w4s[i]=w4[i];
    for(int i=tid;i<768;i+=256) b4s[i]=b4[i];
    if(tid<96) wl3[tid]=w3[tid];
    if(tid<8) bl3[tid]=b3[tid];
    // ---- batch stats reduction (wave 0) ----
    if(tid<64){
        const float* bp=&bpart[((size_t)b*64+tid)*8];
        float sm=bp[0], cmn=bp[1], cmx=bp[2], amn=bp[3], amx=bp[4];
        #pragma unroll
        for(int off=32;off>0;off>>=1){
            sm  += __shfl_down(sm,off);
            cmn  = fminf(cmn,__shfl_down(cmn,off));
            cmx  = fmaxf(cmx,__shfl_down(cmx,off));
            amn  = fminf(amn,__shfl_down(amn,off));
            amx  = fmaxf(amx,__shfl_down(amx,off));
        }
        if(tid==0){
            float den=fmaxf(sm*(1.0f/4096.0f),1e-6f);
            red5[0]=den; red5[1]=cmn; red5[2]=cmx; red5[3]=amn/den; red5[4]=amx/den;
        }
    }
    __syncthreads();
    float den=red5[0], cmn=red5[1], dmn=red5[3];
    float cinv = 1.0f/fmaxf(red5[2]-cmn,1e-6f);
    float dinv = 1.0f/fmaxf(red5[4]-dmn,1e-6f);
    // ---- ev / gm tiles (13 rows), objn tile (3 rows) ----
    for(int j=tid;j<832;j+=256){
        int r=j>>6, x=j&63; int gy=y-6+r;
        float ev=0.f;
        if(gy>=0&&gy<64){
            int gp=(b<<12)+(gy<<6)+x;
            float cs=(csraw[gp]-cmn)*cinv;
            float d=absc[gp]/den;
            ev=0.65f*cs+0.35f*((d-dmn)*dinv);
        }
        evT[j]=ev;
        gmT[j]=sigm_f((ev-0.2f)*(1.0f/0.08f));
    }
    for(int j=tid;j<192;j+=256){
        int r=j>>6,x=j&63; int gy=y-1+r;
        obT[j]=(gy>=0&&gy<64)?sigm_f(objn[(b<<12)+(gy<<6)+x]):0.f;
    }
    __syncthreads();
    // ---- erode rows y-4..y+4 ----
    for(int j=tid;j<576;j+=256){
        int r=j>>6,x=j&63; int gy=y-4+r;
        float m=0.f;
        if(gy>=0&&gy<64){
            m=1.f;
            for(int dy=-2;dy<=2;dy++){int yy=gy+dy; if(yy<0||yy>=64)continue;
                int lr=yy-(y-6);
                for(int dx=-2;dx<=2;dx++){int xx=x+dx; if(xx<0||xx>=64)continue;
                    if(evT[(lr<<6)+xx]<0.2f) m=0.f;}}
        }
        eT[j]=m;
    }
    __syncthreads();
    // ---- dilate e -> m1, rows y-2..y+2 ----
    for(int j=tid;j<320;j+=256){
        int r=j>>6,x=j&63; int gy=y-2+r;
        float m=0.f;
        if(gy>=0&&gy<64){
            m=-1e30f;
            for(int dy=-2;dy<=2;dy++){int yy=gy+dy; if(yy<0||yy>=64)continue;
                int lr=yy-(y-4);
                for(int dx=-2;dx<=2;dx++){int xx=x+dx; if(xx<0||xx>=64)continue;
                    m=fmaxf(m,eT[(lr<<6)+xx]);}}
        }
        m1T[j]=m;
    }
    __syncthreads();
    // ---- phase H: gate finish + h (wave 0, one thread per pixel of row y) ----
    if(tid<64){
        int x=tid;
        int gp=(b<<12)+(y<<6)+x;
        float m2=-1e30f, gx=-1e30f;
        for(int dy=-2;dy<=2;dy++){int yy=y+dy; if(yy<0||yy>=64)continue;
            int lr1=yy-(y-2), lr2=yy-(y-6);
            for(int dx=-2;dx<=2;dx++){int xx=x+dx; if(xx<0||xx>=64)continue;
                m2=fmaxf(m2,m1T[(lr1<<6)+xx]);
                gx=fmaxf(gx,gmT[(lr2<<6)+xx]);}}
        float s=0.f;
        for(int dy=-1;dy<=1;dy++){int yy=y+dy; if(yy<0||yy>=64)continue;
            int lr=yy-(y-1);
            for(int dx=-1;dx<=1;dx++){int xx=x+dx; if(xx<0||xx>=64)continue;
                s+=obT[(lr<<6)+xx];}}
        float blob=s*(1.0f/9.0f);
        float gate=gx*m2;
        float d=absc[gp]/den;
        float sgv=sigm_f(alpha[gp])*blob*gate*(0.7f+0.3f*fminf(fmaxf(d,0.f),2.f));
        // h
        const float* base = ss0 + (b<<12);
        float ssum=0.f;
        for(int dy=-1;dy<=1;dy++){int yy=y+dy; if(yy<0||yy>=64)continue;
            for(int dx=-1;dx<=1;dx++){int xx=x+dx;if(xx<0||xx>=64)continue;
                ssum+=base[(yy<<6)+xx];}}
        float ss1 = base[(y<<6)+x]-ssum*(1.0f/9.0f);
        float cu = tanhf(curv[gp]);
        float ssv = sgv*ss1*(1.0f+0.15f*cu);
        float ta = tanhf(theta[gp])*PI_F;
        float dxv=cosf(ta), dyv=sinf(ta);
        float car[8];
        #pragma unroll
        for(int ci=0;ci<8;ci++) car[ci]=carrier[((size_t)((b<<3)+ci)<<12)+(y<<6)+x];
        #pragma unroll
        for(int co=0;co<8;co++){
            const float* w=&wl3[co*12];
            float t = w[8] + w[9]*dxv + w[10]*dyv + w[11]*cu;
            #pragma unroll
            for(int ci=0;ci<8;ci++) t += w[ci]*car[ci];
            hS[co][tid] = gelu_f(bl3[co] + ssv*t);
        }
    }
    __syncthreads();
    // ---- phase 2: 8->768 expansion, NT stores ----
    int px4 = tid&15;          // f4 px within block
    int cg = tid>>4;           // 0..15, 48 co each
    int q0 = bln*16 + px4;     // GLOBAL f4 index (0..8191)
    int bb_ = q0>>10;
    int ql = q0 & 1023;        // within-batch f4 index
    float4 hv[8];
    #pragma unroll
    for(int ci=0;ci<8;ci++) hv[ci]=*(const float4*)&hS[ci][px4<<2];
    float4* o4=(float4*)out;
    for(int k=0;k<48;k++){
        int co=cg*48+k;
        float bv=b4s[co];
        float4 o=make_float4(bv,bv,bv,bv);
        const float* w=&w4s[co<<3];
        #pragma unroll
        for(int ci=0;ci<8;ci++){
            float wv=w[ci];
            o.x+=wv*hv[ci].x; o.y+=wv*hv[ci].y; o.z+=wv*hv[ci].z; o.w+=wv*hv[ci].w;
        }
        nt_store4(&o4[(size_t)(bb_*768+co)*1024 + ql], o);
    }
}

extern "C" void kernel_launch(void* const* d_in, const int* in_sizes, int n_in,
                              void* d_out, int out_size, void* d_ws, size_t ws_size,
                              hipStream_t stream) {
    const float* fm     =(const float*)d_in[0];
    const float* theta  =(const float*)d_in[1];
    const float* length =(const float*)d_in[2];
    const float* width  =(const float*)d_in[3];
    const float* curv   =(const float*)d_in[4];
    const float* alpha  =(const float*)d_in[5];
    const float* objn   =(const float*)d_in[6];
    const float* plog   =(const float*)d_in[7];
    const float* fp1w   =(const float*)d_in[8];
    const float* fp1b   =(const float*)d_in[9];
    const float* fp2w   =(const float*)d_in[10];
    const float* fp2b   =(const float*)d_in[11];
    const float* pm1w   =(const float*)d_in[12];
    const float* pm1b   =(const float*)d_in[13];
    const float* pm2w   =(const float*)d_in[14];
    const float* pm2b   =(const float*)d_in[15];
    const float* pdelta =(const float*)d_in[16];

    float* ws=(float*)d_ws;
    float* t1      = ws;                  // 262144
    float* carrier = t1 + 262144;         // 262144
    float* absc    = carrier + 262144;    // 32768
    float* csraw   = absc + 32768;        // 32768
    float* ss0     = csraw + 32768;       // 32768
    float* bpart   = ss0 + 32768;         // 4096 (512 records x 8)
    float* klg     = bpart + 4096;        // 648
    float* out     = (float*)d_out;

    k_conv1<<<512, 256, 0, stream>>>(fm, fp1w, fp1b, pdelta, t1, klg);
    k_mid  <<<512, 256, 0, stream>>>(t1, fp2w, fp2b, klg, theta, length, width, plog,
                                     carrier, absc, csraw, ss0, bpart);
    k_out  <<<512, 256, 0, stream>>>(ss0, csraw, absc, objn, alpha, theta, curv,
                                     carrier, bpart, pm1w, pm1b, pm2w, pm2b, out);
}

// Round 12
// 247.323 us; speedup vs baseline: 1.4208x; 1.1486x over previous
//
#include <hip/hip_runtime.h>
#include <math.h>

#define PI_F 3.14159265358979323846f

__device__ __forceinline__ float gelu_f(float x){ return 0.5f*x*(1.0f+erff(x*0.7071067811865475f)); }
__device__ __forceinline__ float sigm_f(float x){ return 1.0f/(1.0f+expf(-x)); }

// native vector type for nontemporal builtins (HIP_vector_type is rejected by the builtin)
typedef float nf4 __attribute__((ext_vector_type(4)));
__device__ __forceinline__ float4 nt_load4(const float4* p){
    nf4 v = __builtin_nontemporal_load((const nf4*)p);
    return make_float4(v.x, v.y, v.z, v.w);
}
__device__ __forceinline__ void nt_store4(float4* p, float4 v){
    nf4 w; w.x=v.x; w.y=v.y; w.z=v.z; w.w=v.w;
    __builtin_nontemporal_store(w, (nf4*)p);
}

// B=8, H=W=64, HW=4096, NP=32768, FC=768, RC=8, P=8, K=9

// ---------------- k_conv1: fp1 1x1 conv 768->8 with IN-BLOCK channel reduction -> t1 ----------------
// grid 512: bln = b*64 + f4chunk; block owns 16 f4 (64 px). 16 groups x 16 threads; group g = ch 48g..48g+47
__global__ void __launch_bounds__(256) k_conv1(const float* __restrict__ fm,
                        const float* __restrict__ w1, const float* __restrict__ b1,
                        const float* __restrict__ pd,
                        float* __restrict__ t1, float* __restrict__ klg){
    __shared__ float wl[768*8];          // 24 KB, wl[c*8+co]
    __shared__ float4 pT[16][8][16];     // 32 KB partials [group][co][f4]
    int bln = blockIdx.x;
    int tid = threadIdx.x;
    int b = bln>>6;
    int q4base = (bln&63)<<4;            // f4 offset within batch plane
    for (int i=tid;i<6144;i+=256){ int c=i>>3, co=i&7; wl[i]=w1[co*768 + c]; }
    __syncthreads();
    int f4i = tid&15, grp = tid>>4;      // grp 0..15
    int q4 = q4base + f4i;
    const float4* fm4 = (const float4*)fm;
    float4 acc[8];
    #pragma unroll
    for(int co=0;co<8;co++) acc[co]=make_float4(0.f,0.f,0.f,0.f);
    int ch0 = grp*48;
    #pragma unroll 4
    for(int c=0;c<48;c++){
        int ch = ch0 + c;
        float4 x = nt_load4(&fm4[(size_t)(b*768 + ch)*1024 + q4]);
        #pragma unroll
        for(int co=0;co<8;co++){
            float wv = wl[(ch<<3)+co];
            acc[co].x += wv*x.x; acc[co].y += wv*x.y; acc[co].z += wv*x.z; acc[co].w += wv*x.w;
        }
    }
    #pragma unroll
    for(int co=0;co<8;co++) pT[grp][co][f4i]=acc[co];
    __syncthreads();
    if(tid<128){
        int co=tid>>4, fi=tid&15;
        float4 s=make_float4(0.f,0.f,0.f,0.f);
        #pragma unroll
        for(int g=0;g<16;g++){
            float4 v=pT[g][co][fi];
            s.x+=v.x; s.y+=v.y; s.z+=v.z; s.w+=v.w;
        }
        float bb=b1[co];
        float4 o;
        o.x=gelu_f(s.x+bb); o.y=gelu_f(s.y+bb); o.z=gelu_f(s.z+bb); o.w=gelu_f(s.w+bb);
        ((float4*)t1)[(size_t)co*8192 + (b<<10) + q4base + fi] = o;
    }

    // ---- bank build (one block only) ----
    if(bln==0){
        __shared__ float ridge[648];
        __shared__ float pmS[8], pdenS[8];
        for(int t=tid;t<648;t+=256){
            int p=t/81, idx=t-p*81;
            int i=idx/9, j=idx-i*9;
            float ay=-1.f+0.25f*(float)i;
            float ax=-1.f+0.25f*(float)j;
            float ang=2.f*PI_F*(float)p*0.125f;
            const float Ls[3]={0.45f,0.75f,1.05f};
            const float Ws[3]={0.14f,0.20f,0.28f};
            float L=Ls[p%3], Wd=Ws[(p/3)%3];
            float cs=cosf(ang), sn=sinf(ang);
            float xr=ax*cs+ay*sn;
            float yr=-ax*sn+ay*cs;
            float tp=1.f-fminf(fabsf(xr)/L,1.f);
            float taper=powf(tp,1.5f);
            float core=expf(-0.5f*((xr/L)*(xr/L)+(yr/Wd)*(yr/Wd)));
            ridge[t]=taper*core*fmaxf(1.f-(yr/Wd)*(yr/Wd),0.f);
        }
        __syncthreads();
        {
            int p=tid>>5, k=tid&31;
            float s=0.f;
            for(int e=k;e<81;e+=32) s+=ridge[p*81+e];
            for(int off=16;off>0;off>>=1) s+=__shfl_down(s,off,32);
            if(k==0) pmS[p]=s*(1.f/81.f);
        }
        __syncthreads();
        {
            int p=tid>>5, k=tid&31;
            float m=pmS[p];
            float s=0.f;
            for(int e=k;e<81;e+=32) s+=fabsf(ridge[p*81+e]-m);
            for(int off=16;off>0;off>>=1) s+=__shfl_down(s,off,32);
            if(k==0) pdenS[p]=fmaxf(s,1e-6f);
        }
        __syncthreads();
        for(int t=tid;t<648;t+=256){
            int p=t/81;
            klg[t]=(ridge[t]-pmS[p])/pdenS[p]+0.05f*pd[t];
        }
    }
}

// ---------------- k_conv2: 3x3 conv 8->8 from t1 -> carrier, cm, absc ----------------
// grid 512: bl = b*64 + y, ONE output row per block
__global__ void __launch_bounds__(256) k_conv2(const float* __restrict__ t1,
    const float* __restrict__ w2, const float* __restrict__ b2,
    float* __restrict__ carrier, float* __restrict__ cm, float* __restrict__ absc,
    float* __restrict__ bpart){
    __shared__ float t1T[8][3][64];  // rows y-1..y+1, 6 KB
    __shared__ float w2s[576];
    __shared__ float sumS[4][64];
    __shared__ float saS[4][64];
    int tid=threadIdx.x, bl=blockIdx.x;
    int b=bl>>6, y=bl&63;
    for(int i=tid;i<576;i+=256) w2s[i]=w2[i];
    // stage t1 rows y-1..y+1 (8 ci x 3 rows x 64) — plain copy, t1 already gelu'd
    for(int j=tid;j<1536;j+=256){
        int ci=j/192, rem=j-ci*192, r=rem>>6, x=rem&63;
        int gy=y-1+r;
        float v=0.f;
        if(gy>=0 && gy<64){
            v = t1[(size_t)ci*32768 + (b<<12)+(gy<<6)+x];
        }
        t1T[ci][r][x]=v;
    }
    __syncthreads();
    int x=tid&63, cg=tid>>6;   // cg 0..3, each owns 2 output channels
    float acc[2];
    #pragma unroll
    for(int qq=0;qq<2;qq++) acc[qq]=b2[cg*2+qq];
    for(int ci=0;ci<8;ci++){
        #pragma unroll
        for(int r=0;r<3;r++){
            #pragma unroll
            for(int dx=-1;dx<=1;dx++){
                int xx=x+dx;
                float v=(xx>=0&&xx<64)?t1T[ci][r][xx]:0.f;
                int ti=r*3+(dx+1);
                #pragma unroll
                for(int qq=0;qq<2;qq++) acc[qq]+=v*w2s[(((cg*2+qq)*8+ci)*9)+ti];
            }
        }
    }
    float s2=0.f, sa2=0.f;
    #pragma unroll
    for(int qq=0;qq<2;qq++){
        float cv=gelu_f(acc[qq]);
        carrier[((size_t)((b<<3)+cg*2+qq)<<12)+(y<<6)+x]=cv;
        s2+=cv; sa2+=fabsf(cv);
    }
    sumS[cg][x]=s2; saS[cg][x]=sa2;
    __syncthreads();
    if(cg==0){   // tid 0..63 = wave 0
        float cmv=(sumS[0][x]+sumS[1][x]+sumS[2][x]+sumS[3][x])*0.125f;
        float av =(saS[0][x]+saS[1][x]+saS[2][x]+saS[3][x])*0.125f;
        int gp=(b<<12)+(y<<6)+x;
        cm[gp]=cmv;
        absc[gp]=av;
        float s=av, mn=av, mx=av;
        #pragma unroll
        for(int off=32;off>0;off>>=1){
            s += __shfl_down(s,off);
            mn = fminf(mn,__shfl_down(mn,off));
            mx = fmaxf(mx,__shfl_down(mx,off));
        }
        if(x==0){
            bpart[bl*8+0]=s;
            bpart[bl*8+3]=mn;
            bpart[bl*8+4]=mx;
        }
    }
}

// ---------------- k_resp: chp + 9x9 bank conv + csraw + top2 softmax ----------------
// grid 512: bl = b*64+y, ONE output row per block; 4 thread-groups x 2 protos
__global__ void __launch_bounds__(256) k_resp(const float* __restrict__ cm,
    const float* __restrict__ klg, const float* __restrict__ theta,
    const float* __restrict__ length, const float* __restrict__ width,
    const float* __restrict__ plog,
    float* __restrict__ csraw, float* __restrict__ ss0, float* __restrict__ bpart){
    __shared__ float cmT[704];       // rows y-5..y+5 (11 rows)
    __shared__ float chpT[576];      // rows y-4..y+4 (9 rows)
    __shared__ float klS[648];
    __shared__ float mg[64][16];
    int tid=threadIdx.x, bl=blockIdx.x;
    int b=bl>>6, y=bl&63;
    for(int i=tid;i<648;i+=256) klS[i]=klg[i];
    for(int j=tid;j<704;j+=256){
        int r=j>>6, x=j&63;
        int gy=y-5+r;
        cmT[j]=(gy>=0&&gy<64)?cm[(b<<12)+(gy<<6)+x]:0.f;
    }
    __syncthreads();
    for(int j=tid;j<576;j+=256){
        int rh=j>>6, x=j&63;      // rh 0..8 <-> gy = y-4+rh, cmT row rh+1
        int gy=y-4+rh;
        float v=0.f;
        if(gy>=0&&gy<64){
            float s=0.f;
            #pragma unroll
            for(int dy=0;dy<3;dy++){
                #pragma unroll
                for(int dx=-1;dx<=1;dx++){
                    int xx=x+dx;
                    if(xx>=0&&xx<64) s+=cmT[(rh+dy)*64+xx];
                }
            }
            v=cmT[(rh+1)*64+x]-s*(1.f/9.f);
        }
        chpT[j]=v;
    }
    __syncthreads();
    int x=tid&63, qg=tid>>6;   // qg 0..3, protos qg*2, qg*2+1
    int gp=(b<<12)+(y<<6)+x;
    float acc[2]={0.f,0.f};
    float cs=0.f;
    for(int dy=-4;dy<=4;dy++){
        int lr=dy+4;
        for(int dx=-4;dx<=4;dx++){
            int xx=x+dx;
            float v=(xx>=0&&xx<64)?chpT[lr*64+xx]:0.f;
            int ti=lr*9+(dx+4);
            acc[0]+=v*klS[(qg*2)*81+ti];
            acc[1]+=v*klS[(qg*2+1)*81+ti];
            if(qg==0 && dy>=-1&&dy<=1&&dx>=-1&&dx<=1) cs+=fabsf(v);
        }
    }
    float ta=tanhf(theta[gp])*PI_F;
    float lv=sigm_f(length[gp])*0.85f+0.25f;
    float wv=sigm_f(width[gp])*0.22f+0.08f;
    const float Ls[3]={0.45f,0.75f,1.05f};
    const float Ws[3]={0.14f,0.20f,0.28f};
    int pp=(y<<6)+x;
    float bias[2];
    #pragma unroll
    for(int qq=0;qq<2;qq++){
        int q=qg*2+qq;
        float ang=2.f*PI_F*(float)q*0.125f;
        float la=Ls[q%3], wa=Ws[(q/3)%3];
        bias[qq]=plog[((size_t)((b<<3)+q)<<12)+pp]
               +1.25f*cosf(ta-ang)
               -(lv-la)*(lv-la)*(1.f/0.08f)
               -(wv-wa)*(wv-wa)*(1.f/0.01f);
    }
    float m1,r1,m2,r2;
    if(bias[1]>bias[0]){ m1=bias[1];r1=acc[1]; m2=bias[0];r2=acc[0]; }
    else               { m1=bias[0];r1=acc[0]; m2=bias[1];r2=acc[1]; }
    mg[x][qg*4+0]=m1; mg[x][qg*4+1]=r1; mg[x][qg*4+2]=m2; mg[x][qg*4+3]=r2;
    __syncthreads();
    if(qg==0){   // wave 0
        float M1=mg[x][0],R1=mg[x][1],M2=mg[x][2],R2=mg[x][3];
        #pragma unroll
        for(int g=1;g<4;g++){
            float m1b=mg[x][g*4],r1b=mg[x][g*4+1],m2b=mg[x][g*4+2],r2b=mg[x][g*4+3];
            if(m1b>M1){
                float nM2,nR2;
                if(m2b>M1){nM2=m2b;nR2=r2b;} else {nM2=M1;nR2=R1;}
                M1=m1b;R1=r1b;M2=nM2;R2=nR2;
            } else if(m1b>M2){
                M2=m1b;R2=r1b;
            }
        }
        float e2=expf(M2-M1);
        float inv=1.0f/(1.0f+e2);
        ss0[gp]=R1*inv + R2*e2*inv;
        float csv=cs*(1.f/9.f);
        csraw[gp]=csv;
        float mn=csv, mx=csv;
        #pragma unroll
        for(int off=32;off>0;off>>=1){
            mn=fminf(mn,__shfl_down(mn,off));
            mx=fmaxf(mx,__shfl_down(mx,off));
        }
        if(x==0){
            bpart[bl*8+1]=mn;
            bpart[bl*8+2]=mx;
        }
    }
}

// ---------------- k_out: gate + h + pm2 fused; grid 512 (1 row / block); w4/b4 read direct ----------------
__global__ void __launch_bounds__(256) k_out(const float* __restrict__ ss0,
    const float* __restrict__ csraw, const float* __restrict__ absc,
    const float* __restrict__ objn, const float* __restrict__ alpha,
    const float* __restrict__ theta, const float* __restrict__ curv,
    const float* __restrict__ carrier, const float* __restrict__ bpart,
    const float* __restrict__ w3, const float* __restrict__ b3,
    const float* __restrict__ w4, const float* __restrict__ b4,
    float* __restrict__ out){
    __shared__ float hS[8][64];      // 2 KB
    __shared__ float wl3[96];
    __shared__ float bl3[8];
    __shared__ float evT[13*64];     // ev rows y-6..y+6
    __shared__ float gmT[13*64];     // sigm gate, same rows
    __shared__ float eT[9*64];       // erode rows y-4..y+4
    __shared__ float m1T[5*64];      // dilate rows y-2..y+2
    __shared__ float obT[3*64];      // sigm(objn) rows y-1..y+1
    __shared__ float red5[5];
    int tid=threadIdx.x;
    int bln=blockIdx.x;              // 0..511
    int b=bln>>6, y=bln&63;
    if(tid<96) wl3[tid]=w3[tid];
    if(tid<8) bl3[tid]=b3[tid];
    // ---- batch stats reduction (wave 0... tid 64..127 to overlap with wl3 load waves) ----
    if(tid<64){
        const float* bp=&bpart[((size_t)b*64+tid)*8];
        float sm=bp[0], cmn=bp[1], cmx=bp[2], amn=bp[3], amx=bp[4];
        #pragma unroll
        for(int off=32;off>0;off>>=1){
            sm  += __shfl_down(sm,off);
            cmn  = fminf(cmn,__shfl_down(cmn,off));
            cmx  = fmaxf(cmx,__shfl_down(cmx,off));
            amn  = fminf(amn,__shfl_down(amn,off));
            amx  = fmaxf(amx,__shfl_down(amx,off));
        }
        if(tid==0){
            float den=fmaxf(sm*(1.0f/4096.0f),1e-6f);
            red5[0]=den; red5[1]=cmn; red5[2]=cmx; red5[3]=amn/den; red5[4]=amx/den;
        }
    }
    __syncthreads();
    float den=red5[0], cmn=red5[1], dmn=red5[3];
    float cinv = 1.0f/fmaxf(red5[2]-cmn,1e-6f);
    float dinv = 1.0f/fmaxf(red5[4]-dmn,1e-6f);
    // ---- ev / gm tiles (13 rows), objn tile (3 rows) ----
    for(int j=tid;j<832;j+=256){
        int r=j>>6, x=j&63; int gy=y-6+r;
        float ev=0.f;
        if(gy>=0&&gy<64){
            int gp=(b<<12)+(gy<<6)+x;
            float cs=(csraw[gp]-cmn)*cinv;
            float d=absc[gp]/den;
            ev=0.65f*cs+0.35f*((d-dmn)*dinv);
        }
        evT[j]=ev;
        gmT[j]=sigm_f((ev-0.2f)*(1.0f/0.08f));
    }
    for(int j=tid;j<192;j+=256){
        int r=j>>6,x=j&63; int gy=y-1+r;
        obT[j]=(gy>=0&&gy<64)?sigm_f(objn[(b<<12)+(gy<<6)+x]):0.f;
    }
    __syncthreads();
    // ---- erode rows y-4..y+4 ----
    for(int j=tid;j<576;j+=256){
        int r=j>>6,x=j&63; int gy=y-4+r;
        float m=0.f;
        if(gy>=0&&gy<64){
            m=1.f;
            for(int dy=-2;dy<=2;dy++){int yy=gy+dy; if(yy<0||yy>=64)continue;
                int lr=yy-(y-6);
                for(int dx=-2;dx<=2;dx++){int xx=x+dx; if(xx<0||xx>=64)continue;
                    if(evT[(lr<<6)+xx]<0.2f) m=0.f;}}
        }
        eT[j]=m;
    }
    __syncthreads();
    // ---- dilate e -> m1, rows y-2..y+2 ----
    for(int j=tid;j<320;j+=256){
        int r=j>>6,x=j&63; int gy=y-2+r;
        float m=0.f;
        if(gy>=0&&gy<64){
            m=-1e30f;
            for(int dy=-2;dy<=2;dy++){int yy=gy+dy; if(yy<0||yy>=64)continue;
                int lr=yy-(y-4);
                for(int dx=-2;dx<=2;dx++){int xx=x+dx; if(xx<0||xx>=64)continue;
                    m=fmaxf(m,eT[(lr<<6)+xx]);}}
        }
        m1T[j]=m;
    }
    __syncthreads();
    // ---- phase H: gate finish + h (wave 0, one thread per pixel of row y) ----
    if(tid<64){
        int x=tid;
        int gp=(b<<12)+(y<<6)+x;
        float m2=-1e30f, gx=-1e30f;
        for(int dy=-2;dy<=2;dy++){int yy=y+dy; if(yy<0||yy>=64)continue;
            int lr1=yy-(y-2), lr2=yy-(y-6);
            for(int dx=-2;dx<=2;dx++){int xx=x+dx; if(xx<0||xx>=64)continue;
                m2=fmaxf(m2,m1T[(lr1<<6)+xx]);
                gx=fmaxf(gx,gmT[(lr2<<6)+xx]);}}
        float s=0.f;
        for(int dy=-1;dy<=1;dy++){int yy=y+dy; if(yy<0||yy>=64)continue;
            int lr=yy-(y-1);
            for(int dx=-1;dx<=1;dx++){int xx=x+dx; if(xx<0||xx>=64)continue;
                s+=obT[(lr<<6)+xx];}}
        float blob=s*(1.0f/9.0f);
        float gate=gx*m2;
        float d=absc[gp]/den;
        float sgv=sigm_f(alpha[gp])*blob*gate*(0.7f+0.3f*fminf(fmaxf(d,0.f),2.f));
        // h
        const float* base = ss0 + (b<<12);
        float ssum=0.f;
        for(int dy=-1;dy<=1;dy++){int yy=y+dy; if(yy<0||yy>=64)continue;
            for(int dx=-1;dx<=1;dx++){int xx=x+dx;if(xx<0||xx>=64)continue;
                ssum+=base[(yy<<6)+xx];}}
        float ss1 = base[(y<<6)+x]-ssum*(1.0f/9.0f);
        float cu = tanhf(curv[gp]);
        float ssv = sgv*ss1*(1.0f+0.15f*cu);
        float ta = tanhf(theta[gp])*PI_F;
        float dxv=cosf(ta), dyv=sinf(ta);
        float car[8];
        #pragma unroll
        for(int ci=0;ci<8;ci++) car[ci]=carrier[((size_t)((b<<3)+ci)<<12)+(y<<6)+x];
        #pragma unroll
        for(int co=0;co<8;co++){
            const float* w=&wl3[co*12];
            float t = w[8] + w[9]*dxv + w[10]*dyv + w[11]*cu;
            #pragma unroll
            for(int ci=0;ci<8;ci++) t += w[ci]*car[ci];
            hS[co][tid] = gelu_f(bl3[co] + ssv*t);
        }
    }
    __syncthreads();
    // ---- phase 2: 8->768 expansion, w4/b4 read direct from L1/L2, NT stores ----
    int px4 = tid&15;          // f4 px within block
    int cg = tid>>4;           // 0..15, 48 co each
    int q0 = bln*16 + px4;     // GLOBAL f4 index (0..8191)
    int bb_ = q0>>10;
    int ql = q0 & 1023;        // within-batch f4 index
    float4 hv[8];
    #pragma unroll
    for(int ci=0;ci<8;ci++) hv[ci]=*(const float4*)&hS[ci][px4<<2];
    float4* o4=(float4*)out;
    for(int k=0;k<48;k++){
        int co=cg*48+k;
        float bv=b4[co];
        float4 o=make_float4(bv,bv,bv,bv);
        const float* w=&w4[co<<3];
        #pragma unroll
        for(int ci=0;ci<8;ci++){
            float wv=w[ci];
            o.x+=wv*hv[ci].x; o.y+=wv*hv[ci].y; o.z+=wv*hv[ci].z; o.w+=wv*hv[ci].w;
        }
        nt_store4(&o4[(size_t)(bb_*768+co)*1024 + ql], o);
    }
}

extern "C" void kernel_launch(void* const* d_in, const int* in_sizes, int n_in,
                              void* d_out, int out_size, void* d_ws, size_t ws_size,
                              hipStream_t stream) {
    const float* fm     =(const float*)d_in[0];
    const float* theta  =(const float*)d_in[1];
    const float* length =(const float*)d_in[2];
    const float* width  =(const float*)d_in[3];
    const float* curv   =(const float*)d_in[4];
    const float* alpha  =(const float*)d_in[5];
    const float* objn   =(const float*)d_in[6];
    const float* plog   =(const float*)d_in[7];
    const float* fp1w   =(const float*)d_in[8];
    const float* fp1b   =(const float*)d_in[9];
    const float* fp2w   =(const float*)d_in[10];
    const float* fp2b   =(const float*)d_in[11];
    const float* pm1w   =(const float*)d_in[12];
    const float* pm1b   =(const float*)d_in[13];
    const float* pm2w   =(const float*)d_in[14];
    const float* pm2b   =(const float*)d_in[15];
    const float* pdelta =(const float*)d_in[16];

    float* ws=(float*)d_ws;
    float* t1      = ws;                  // 262144
    float* carrier = t1 + 262144;         // 262144
    float* absc    = carrier + 262144;    // 32768
    float* csraw   = absc + 32768;        // 32768
    float* ss0     = csraw + 32768;       // 32768
    float* cm      = ss0 + 32768;         // 32768
    float* bpart   = cm + 32768;          // 4096 (512 records x 8)
    float* klg     = bpart + 4096;        // 648
    float* out     = (float*)d_out;

    k_conv1<<<512, 256, 0, stream>>>(fm, fp1w, fp1b, pdelta, t1, klg);
    k_conv2<<<512, 256, 0, stream>>>(t1, fp2w, fp2b, carrier, cm, absc, bpart);
    k_resp <<<512, 256, 0, stream>>>(cm, klg, theta, length, width, plog,
                                     csraw, ss0, bpart);
    k_out  <<<512, 256, 0, stream>>>(ss0, csraw, absc, objn, alpha, theta, curv,
                                     carrier, bpart, pm1w, pm1b, pm2w, pm2b, out);
}